// Round 5
// baseline (644.294 us; speedup 1.0000x reference)
//
#include <hip/hip_runtime.h>
#include <hip/hip_bf16.h>
#include <math.h>

typedef __hip_bfloat16 bf16;
typedef __attribute__((ext_vector_type(8))) short bf16x8;
typedef __attribute__((ext_vector_type(4))) float f32x4;

__device__ __forceinline__ float b2f(bf16 x) { return __bfloat162float(x); }
__device__ __forceinline__ float us2f(unsigned short u) {
    return __uint_as_float(((unsigned int)u) << 16);
}
__device__ __forceinline__ unsigned short f2us(float f) {
    bf16 t = __float2bfloat16(f);
    return *reinterpret_cast<unsigned short*>(&t);
}
__device__ __forceinline__ float scrub(float v) {
    return (v == v && fabsf(v) < 3.0e38f) ? v : 0.f;
}
__device__ __forceinline__ float to_float(float x) { return x; }
__device__ __forceinline__ float to_float(bf16 x) { return __bfloat162float(x); }
__device__ __forceinline__ void store_out(float* p, float v) { *p = v; }
__device__ __forceinline__ void store_out(bf16* p, float v) { *p = __float2bfloat16(v); }

// ---------------------------------------------------------------------------
// Convert all 18 fp32 input tensors into one contiguous bf16 region.
// (fp32 storage confirmed by round-2/3 bisection; output is fp32 per the
// harness contract "reference's OUTPUT dtype ... else float*".)
// ---------------------------------------------------------------------------
struct Ptrs { const void* p[18]; };

__constant__ __device__ const long TOFF[19] = {
    0,         2097152,  2098176,  2099200,  6293504,  6301696,  6303744,
    6500352,   6631424,  6633472,  6666240,  6668288,  8765440,  8766464,
    8767488,   10864640, 10866688, 12963840, 12964864};

__global__ __launch_bounds__(256) void convert_kernel(
    Ptrs ptrs, unsigned short* __restrict__ dst)
{
    const long g = (long)blockIdx.x * 256 + threadIdx.x;
    if (g >= 1620608) return;            // 12,964,864 / 8
    const long e0 = g * 8;
    int t = 0;
    #pragma unroll
    for (int i = 1; i < 18; ++i) t += (e0 >= TOFF[i]) ? 1 : 0;
    const long local = e0 - TOFF[t];
    const float4* ps = (const float4*)((const float*)ptrs.p[t] + local);
    const float4 a = ps[0], b = ps[1];
    ushort4 o0, o1;
    o0.x = f2us(a.x); o0.y = f2us(a.y); o0.z = f2us(a.z); o0.w = f2us(a.w);
    o1.x = f2us(b.x); o1.y = f2us(b.y); o1.z = f2us(b.z); o1.w = f2us(b.w);
    *(ushort4*)(dst + e0)     = o0;
    *(ushort4*)(dst + e0 + 4) = o1;
}

// ---------------------------------------------------------------------------
// LayerNorm: one block per row of 1024, 256 threads x 4 elems.
// ---------------------------------------------------------------------------
template <typename TIN>
__global__ __launch_bounds__(256) void ln_kernel(
    const TIN* __restrict__ in, const bf16* __restrict__ gw,
    const bf16* __restrict__ gb, bf16* __restrict__ out)
{
    const int row = blockIdx.x;
    const int tid = threadIdx.x;
    float v[4];
    if constexpr (sizeof(TIN) == 2) {
        ushort4 raw = ((const ushort4*)((const unsigned short*)in + (long)row * 1024))[tid];
        v[0] = us2f(raw.x); v[1] = us2f(raw.y); v[2] = us2f(raw.z); v[3] = us2f(raw.w);
    } else {
        float4 raw = ((const float4*)((const float*)in + (long)row * 1024))[tid];
        v[0] = raw.x; v[1] = raw.y; v[2] = raw.z; v[3] = raw.w;
    }
    float s  = v[0] + v[1] + v[2] + v[3];
    float s2 = v[0]*v[0] + v[1]*v[1] + v[2]*v[2] + v[3]*v[3];
    #pragma unroll
    for (int o = 32; o > 0; o >>= 1) {
        s  += __shfl_xor(s, o);
        s2 += __shfl_xor(s2, o);
    }
    __shared__ float red[8];
    if ((tid & 63) == 0) { red[tid >> 6] = s; red[4 + (tid >> 6)] = s2; }
    __syncthreads();
    s  = red[0] + red[1] + red[2] + red[3];
    s2 = red[4] + red[5] + red[6] + red[7];
    const float mu  = s * (1.f / 1024.f);
    const float var = fmaxf(s2 * (1.f / 1024.f) - mu * mu, 0.f);
    const float rs  = rsqrtf(var + 1e-5f);
    const int c0 = tid * 4;
    ushort4 o;
    o.x = f2us((v[0] - mu) * rs * b2f(gw[c0 + 0]) + b2f(gb[c0 + 0]));
    o.y = f2us((v[1] - mu) * rs * b2f(gw[c0 + 1]) + b2f(gb[c0 + 1]));
    o.z = f2us((v[2] - mu) * rs * b2f(gw[c0 + 2]) + b2f(gb[c0 + 2]));
    o.w = f2us((v[3] - mu) * rs * b2f(gw[c0 + 3]) + b2f(gb[c0 + 3]));
    ((ushort4*)((unsigned short*)out + (long)row * 1024))[tid] = o;
}

// ---------------------------------------------------------------------------
// GEMM: C[M,N] = act(A[M,K] * Bw[N,K]^T + bias) + res.  bf16 in, fp32 acc.
// 128x128 tile, BK=64, 4 waves of 4x4 mfma_f32_16x16x32_bf16.
// ACT: 0=none, 1=gelu(exact), 2=softplus
// ---------------------------------------------------------------------------
template <int ACT, typename TOUT, typename TRES>
__global__ __launch_bounds__(256) void gemm_bt(
    const bf16* __restrict__ A, int lda,
    const bf16* __restrict__ Bw, int ldb,
    TOUT* __restrict__ C, int ldc,
    const bf16* __restrict__ bias,
    const TRES* __restrict__ res,
    int M, int N, int K)
{
    __shared__ __align__(16) short As[128][72];  // 64 k + 8 pad
    __shared__ __align__(16) short Bs[128][72];
    const int tid  = threadIdx.x;
    const int lane = tid & 63;
    const int wave = tid >> 6;
    const int m0 = blockIdx.y * 128;
    const int n0 = blockIdx.x * 128;
    const int wm = (wave >> 1) * 64;
    const int wn = (wave & 1) * 64;
    const int lr = lane & 15;
    const int lq = lane >> 4;

    const int sr = tid >> 1;          // staging row 0..127
    const int sc = (tid & 1) * 32;    // staging k-offset (shorts)

    f32x4 acc[4][4] = {};

    for (int k0 = 0; k0 < K; k0 += 64) {
        const uint4* pa = (const uint4*)(A + (long)(m0 + sr) * lda + (k0 + sc));
        uint4 a0 = pa[0], a1 = pa[1], a2 = pa[2], a3 = pa[3];
        uint4 b0, b1, b2, b3;
        b0.x=b0.y=b0.z=b0.w=0; b1=b0; b2=b0; b3=b0;
        if (n0 + sr < N) {
            const uint4* pb = (const uint4*)(Bw + (long)(n0 + sr) * ldb + (k0 + sc));
            b0 = pb[0]; b1 = pb[1]; b2 = pb[2]; b3 = pb[3];
        }
        *(uint4*)&As[sr][sc +  0] = a0;
        *(uint4*)&As[sr][sc +  8] = a1;
        *(uint4*)&As[sr][sc + 16] = a2;
        *(uint4*)&As[sr][sc + 24] = a3;
        *(uint4*)&Bs[sr][sc +  0] = b0;
        *(uint4*)&Bs[sr][sc +  8] = b1;
        *(uint4*)&Bs[sr][sc + 16] = b2;
        *(uint4*)&Bs[sr][sc + 24] = b3;
        __syncthreads();

        #pragma unroll
        for (int kk = 0; kk < 2; ++kk) {
            bf16x8 af[4], bfr[4];
            #pragma unroll
            for (int i = 0; i < 4; ++i)
                af[i] = *(const bf16x8*)&As[wm + i * 16 + lr][kk * 32 + lq * 8];
            #pragma unroll
            for (int j = 0; j < 4; ++j)
                bfr[j] = *(const bf16x8*)&Bs[wn + j * 16 + lr][kk * 32 + lq * 8];
            #pragma unroll
            for (int i = 0; i < 4; ++i)
                #pragma unroll
                for (int j = 0; j < 4; ++j)
                    acc[i][j] = __builtin_amdgcn_mfma_f32_16x16x32_bf16(
                        af[i], bfr[j], acc[i][j], 0, 0, 0);
        }
        __syncthreads();
    }

    // Epilogue.  C/D layout: col = lane&15, row = (lane>>4)*4 + reg.
    #pragma unroll
    for (int j = 0; j < 4; ++j) {
        const int col = n0 + wn + j * 16 + lr;
        if (col >= N) continue;
        const float bv = bias ? b2f(bias[col]) : 0.f;
        #pragma unroll
        for (int i = 0; i < 4; ++i) {
            const int r0 = m0 + wm + i * 16 + lq * 4;
            #pragma unroll
            for (int r = 0; r < 4; ++r) {
                const long row = r0 + r;
                float v = acc[i][j][r] + bv;
                if constexpr (ACT == 1) v = 0.5f * v * (1.f + erff(v * 0.70710678118f));
                if constexpr (ACT == 2) v = (v > 20.f) ? v : log1pf(__expf(v));
                if (res) v += to_float(res[row * ldc + col]);
                store_out(&C[row * ldc + col], scrub(v));
            }
        }
    }
}

// ---------------------------------------------------------------------------
// Depthwise causal conv (window 4) + bias + silu.  u = xz[:, 0:2048].
// ---------------------------------------------------------------------------
__global__ __launch_bounds__(256) void conv_silu_kernel(
    const bf16* __restrict__ xz, const bf16* __restrict__ cw,
    const bf16* __restrict__ cb, bf16* __restrict__ uc)
{
    const int gid = blockIdx.x * 256 + threadIdx.x;   // over 2*1024*2048
    const int d   = gid & 2047;
    const int row = gid >> 11;                        // b*1024 + t
    const int t   = row & 1023;
    float acc = b2f(cb[d]);
    #pragma unroll
    for (int j = 0; j < 4; ++j) {
        const int tt = t - 3 + j;
        if (tt >= 0)
            acc += b2f(cw[d * 4 + j]) * b2f(xz[(long)(row - 3 + j) * 4096 + d]);
    }
    const float sg = 1.f / (1.f + __expf(-acc));
    uc[gid] = __float2bfloat16(acc * sg);
}

// ---------------------------------------------------------------------------
// Selective scan.  Lane-per-(d,n): n = tid&15, d = d0 + (tid>>4).
// Chunked LDS staging (64 timesteps).  y = (scan_y + u*D) * silu(z).
// y aliases delta element-for-element (each block writes only its own
// rows x cols after reading them, with barriers between) — safe.
// ---------------------------------------------------------------------------
__global__ __launch_bounds__(256) void scan_kernel(
    const bf16* __restrict__ delta,    // (B*L, 2048)
    const bf16* __restrict__ uc,       // (B*L, 2048)
    const bf16* __restrict__ dbc,      // (B*L, 96): dt | B | C
    const bf16* __restrict__ xz,       // (B*L, 4096): z at cols 2048+d
    const float* __restrict__ A_log,   // (2048, 16) fp32 original
    const float* __restrict__ Dp,      // (2048)     fp32 original
    bf16* __restrict__ y)              // (B*L, 2048)
{
    const int b   = blockIdx.y;
    const int d0  = blockIdx.x * 16;
    const int tid = threadIdx.x;
    const int n   = tid & 15;
    const int dl  = tid >> 4;          // 0..15
    const int d   = d0 + dl;

    __shared__ float sD[64][16];
    __shared__ float sU[64][16];
    __shared__ float sB[64][16];
    __shared__ float sC[64][16];
    __shared__ float sZ[64][16];
    __shared__ float sY[64][16];

    const float An = -expf(A_log[d * 16 + n]);
    const float Dd = Dp[d];
    float h = 0.f;
    const long rowbase = (long)b * 1024;

    for (int t0 = 0; t0 < 1024; t0 += 64) {
        // ---- staging ----
        for (int i = tid; i < 1024; i += 256) {
            const int tt = i >> 4, dd = i & 15;
            const long r = rowbase + t0 + tt;
            sD[tt][dd] = b2f(delta[r * 2048 + d0 + dd]);
            sU[tt][dd] = b2f(uc[r * 2048 + d0 + dd]);
            sB[tt][dd] = b2f(dbc[r * 96 + 64 + dd]);
            sC[tt][dd] = b2f(dbc[r * 96 + 80 + dd]);
            const float zz = b2f(xz[r * 4096 + 2048 + d0 + dd]);
            sZ[tt][dd] = zz / (1.f + __expf(-zz));
        }
        __syncthreads();

        // ---- sequential steps ----
        for (int t = 0; t < 64; ++t) {
            const float dt = sD[t][dl];
            const float a  = __expf(dt * An);
            const float uv = sU[t][dl];
            h = a * h + dt * uv * sB[t][n];
            float p = h * sC[t][n];
            p += __shfl_xor(p, 1);
            p += __shfl_xor(p, 2);
            p += __shfl_xor(p, 4);
            p += __shfl_xor(p, 8);
            if (n == 0)
                sY[t][dl] = (p + uv * Dd) * sZ[t][dl];
        }
        __syncthreads();

        // ---- coalesced write-out ----
        for (int i = tid; i < 1024; i += 256) {
            const int tt = i >> 4, dd = i & 15;
            y[(rowbase + t0 + tt) * 2048 + d0 + dd] = __float2bfloat16(sY[tt][dd]);
        }
        __syncthreads();
    }
}

// ---------------------------------------------------------------------------
extern "C" void kernel_launch(void* const* d_in, const int* in_sizes, int n_in,
                              void* d_out, int out_size, void* d_ws, size_t ws_size,
                              hipStream_t stream)
{
    char* ws = (char*)d_ws;
    const size_t MiB = 1048576;

    // Pipeline scratch (time-multiplexed overlays):
    bf16*  xn  = (bf16*)(ws);                    // [ 0, 4): (2048,1024) ln1 out
    bf16*  xz  = (bf16*)(ws +  4 * MiB);         // [ 4,20): (2048,4096) in_proj out
    bf16*  uc  = (bf16*)(ws + 20 * MiB);         // [20,28): (2048,2048) conv+silu out
    bf16*  dbc = (bf16*)(ws + 28 * MiB);         // [28,28.4): (2048,96)
    bf16*  dlb = (bf16*)(ws + 28 * MiB + 524288);// [28.5,36.5): delta; scan writes y in-place
    bf16*  yb  = dlb;                            //   (element-aliased, safe)
    float* hb  = (float*)(ws);                   // [ 0, 8): f32 resid (xn/xz dead at step 7)
    bf16*  hn  = (bf16*)(ws +  8 * MiB);         // [ 8,12): ln2 out (over dead xz)
    bf16*  gb  = (bf16*)(ws + 12 * MiB);         // [12,20): mlp1 out (over dead xz)
    unsigned short* cvt = (unsigned short*)(ws + 37 * MiB);  // [37, 61.8): bf16 inputs

    // fp32 originals used directly (residual-path accuracy):
    const float* xf     = (const float*)d_in[0];
    const float* A_logf = (const float*)d_in[9];
    const float* Dpf    = (const float*)d_in[10];

    // Converted-input pointers (element offsets per TOFF).
    const bf16* ln1_w      = (const bf16*)(cvt + 2097152);
    const bf16* ln1_b      = (const bf16*)(cvt + 2098176);
    const bf16* in_proj_w  = (const bf16*)(cvt + 2099200);
    const bf16* conv_w     = (const bf16*)(cvt + 6293504);
    const bf16* conv_b     = (const bf16*)(cvt + 6301696);
    const bf16* x_proj_w   = (const bf16*)(cvt + 6303744);
    const bf16* dt_proj_w  = (const bf16*)(cvt + 6500352);
    const bf16* dt_proj_b  = (const bf16*)(cvt + 6631424);
    const bf16* out_proj_w = (const bf16*)(cvt + 6668288);
    const bf16* ln2_w      = (const bf16*)(cvt + 8765440);
    const bf16* ln2_b      = (const bf16*)(cvt + 8766464);
    const bf16* mlp_w1     = (const bf16*)(cvt + 8767488);
    const bf16* mlp_b1     = (const bf16*)(cvt + 10864640);
    const bf16* mlp_w2     = (const bf16*)(cvt + 10866688);
    const bf16* mlp_b2     = (const bf16*)(cvt + 12963840);

    // 0. input normalization fp32 -> bf16
    Ptrs ptrs;
    for (int i = 0; i < 18; ++i) ptrs.p[i] = d_in[i];
    convert_kernel<<<6332, 256, 0, stream>>>(ptrs, cvt);

    // 1. LN1 (reads fp32 x directly)
    ln_kernel<float><<<2048, 256, 0, stream>>>(xf, ln1_w, ln1_b, xn);
    // 2. in_proj: xz = xn @ in_proj_w^T   (2048,4096,K=1024)
    gemm_bt<0, bf16, bf16><<<dim3(32, 16), 256, 0, stream>>>(
        xn, 1024, in_proj_w, 1024, xz, 4096, nullptr, (const bf16*)nullptr, 2048, 4096, 1024);
    // 3. depthwise causal conv + bias + silu -> uc
    conv_silu_kernel<<<16384, 256, 0, stream>>>(xz, conv_w, conv_b, uc);
    // 4. x_proj: dbc = uc @ x_proj_w^T    (2048,96,K=2048)
    gemm_bt<0, bf16, bf16><<<dim3(1, 16), 256, 0, stream>>>(
        uc, 2048, x_proj_w, 2048, dbc, 96, nullptr, (const bf16*)nullptr, 2048, 96, 2048);
    // 5. dt_proj + softplus: delta = softplus(dbc[:, :64] @ dt_proj_w^T + b)
    gemm_bt<2, bf16, bf16><<<dim3(16, 16), 256, 0, stream>>>(
        dbc, 96, dt_proj_w, 64, dlb, 2048, dt_proj_b, (const bf16*)nullptr, 2048, 2048, 64);
    // 6. selective scan -> yb (in-place over dlb)
    scan_kernel<<<dim3(128, 2), 256, 0, stream>>>(dlb, uc, dbc, xz, A_logf, Dpf, yb);
    // 7. out_proj + residual x (fp32): hb = yb @ out_proj_w^T + x
    gemm_bt<0, float, float><<<dim3(8, 16), 256, 0, stream>>>(
        yb, 2048, out_proj_w, 2048, hb, 1024, nullptr, xf, 2048, 1024, 2048);
    // 8. LN2
    ln_kernel<float><<<2048, 256, 0, stream>>>(hb, ln2_w, ln2_b, hn);
    // 9. MLP1 + gelu: gb = gelu(hn @ mlp_w1^T + b1)
    gemm_bt<1, bf16, bf16><<<dim3(16, 16), 256, 0, stream>>>(
        hn, 1024, mlp_w1, 1024, gb, 2048, mlp_b1, (const bf16*)nullptr, 2048, 2048, 1024);
    // 10. MLP2 + bias + residual h -> d_out (fp32)
    gemm_bt<0, float, float><<<dim3(8, 16), 256, 0, stream>>>(
        gb, 2048, mlp_w2, 2048, (float*)d_out, 1024, mlp_b2, hb, 2048, 1024, 2048);
}

// Round 6
// 634.520 us; speedup vs baseline: 1.0154x; 1.0154x over previous
//
#include <hip/hip_runtime.h>
#include <hip/hip_bf16.h>
#include <math.h>

typedef __hip_bfloat16 bf16;
typedef __attribute__((ext_vector_type(8))) short bf16x8;
typedef __attribute__((ext_vector_type(4))) float f32x4;

__device__ __forceinline__ float b2f(bf16 x) { return __bfloat162float(x); }
__device__ __forceinline__ float us2f(unsigned short u) {
    return __uint_as_float(((unsigned int)u) << 16);
}
__device__ __forceinline__ unsigned short f2us(float f) {
    bf16 t = __float2bfloat16(f);
    return *reinterpret_cast<unsigned short*>(&t);
}
__device__ __forceinline__ float scrub(float v) {
    return (v == v && fabsf(v) < 3.0e38f) ? v : 0.f;
}
__device__ __forceinline__ float to_float(float x) { return x; }
__device__ __forceinline__ float to_float(bf16 x) { return __bfloat162float(x); }
__device__ __forceinline__ void store_out(float* p, float v) { *p = v; }
__device__ __forceinline__ void store_out(bf16* p, float v) { *p = __float2bfloat16(v); }

// ---------------------------------------------------------------------------
// Convert all 18 fp32 input tensors into one contiguous bf16 region.
// ---------------------------------------------------------------------------
struct Ptrs { const void* p[18]; };

__constant__ __device__ const long TOFF[19] = {
    0,         2097152,  2098176,  2099200,  6293504,  6301696,  6303744,
    6500352,   6631424,  6633472,  6666240,  6668288,  8765440,  8766464,
    8767488,   10864640, 10866688, 12963840, 12964864};

__global__ __launch_bounds__(256) void convert_kernel(
    Ptrs ptrs, unsigned short* __restrict__ dst)
{
    const long g = (long)blockIdx.x * 256 + threadIdx.x;
    if (g >= 1620608) return;            // 12,964,864 / 8
    const long e0 = g * 8;
    int t = 0;
    #pragma unroll
    for (int i = 1; i < 18; ++i) t += (e0 >= TOFF[i]) ? 1 : 0;
    const long local = e0 - TOFF[t];
    const float4* ps = (const float4*)((const float*)ptrs.p[t] + local);
    const float4 a = ps[0], b = ps[1];
    ushort4 o0, o1;
    o0.x = f2us(a.x); o0.y = f2us(a.y); o0.z = f2us(a.z); o0.w = f2us(a.w);
    o1.x = f2us(b.x); o1.y = f2us(b.y); o1.z = f2us(b.z); o1.w = f2us(b.w);
    *(ushort4*)(dst + e0)     = o0;
    *(ushort4*)(dst + e0 + 4) = o1;
}

// ---------------------------------------------------------------------------
// LayerNorm: one block per row of 1024, 256 threads x 4 elems.
// ---------------------------------------------------------------------------
template <typename TIN>
__global__ __launch_bounds__(256) void ln_kernel(
    const TIN* __restrict__ in, const bf16* __restrict__ gw,
    const bf16* __restrict__ gb, bf16* __restrict__ out)
{
    const int row = blockIdx.x;
    const int tid = threadIdx.x;
    float v[4];
    if constexpr (sizeof(TIN) == 2) {
        ushort4 raw = ((const ushort4*)((const unsigned short*)in + (long)row * 1024))[tid];
        v[0] = us2f(raw.x); v[1] = us2f(raw.y); v[2] = us2f(raw.z); v[3] = us2f(raw.w);
    } else {
        float4 raw = ((const float4*)((const float*)in + (long)row * 1024))[tid];
        v[0] = raw.x; v[1] = raw.y; v[2] = raw.z; v[3] = raw.w;
    }
    float s  = v[0] + v[1] + v[2] + v[3];
    float s2 = v[0]*v[0] + v[1]*v[1] + v[2]*v[2] + v[3]*v[3];
    #pragma unroll
    for (int o = 32; o > 0; o >>= 1) {
        s  += __shfl_xor(s, o);
        s2 += __shfl_xor(s2, o);
    }
    __shared__ float red[8];
    if ((tid & 63) == 0) { red[tid >> 6] = s; red[4 + (tid >> 6)] = s2; }
    __syncthreads();
    s  = red[0] + red[1] + red[2] + red[3];
    s2 = red[4] + red[5] + red[6] + red[7];
    const float mu  = s * (1.f / 1024.f);
    const float var = fmaxf(s2 * (1.f / 1024.f) - mu * mu, 0.f);
    const float rs  = rsqrtf(var + 1e-5f);
    const int c0 = tid * 4;
    ushort4 o;
    o.x = f2us((v[0] - mu) * rs * b2f(gw[c0 + 0]) + b2f(gb[c0 + 0]));
    o.y = f2us((v[1] - mu) * rs * b2f(gw[c0 + 1]) + b2f(gb[c0 + 1]));
    o.z = f2us((v[2] - mu) * rs * b2f(gw[c0 + 2]) + b2f(gb[c0 + 2]));
    o.w = f2us((v[3] - mu) * rs * b2f(gw[c0 + 3]) + b2f(gb[c0 + 3]));
    ((ushort4*)((unsigned short*)out + (long)row * 1024))[tid] = o;
}

// ---------------------------------------------------------------------------
// GEMM: C[M,N] = act(A[M,K] * Bw[N,K]^T + bias) + res.  bf16 in, fp32 acc.
// 128x128 tile, BK=64, 4 waves of 4x4 mfma_f32_16x16x32_bf16.
// ACT: 0=none, 1=gelu(exact), 2=softplus
// ---------------------------------------------------------------------------
template <int ACT, typename TOUT, typename TRES>
__global__ __launch_bounds__(256) void gemm_bt(
    const bf16* __restrict__ A, int lda,
    const bf16* __restrict__ Bw, int ldb,
    TOUT* __restrict__ C, int ldc,
    const bf16* __restrict__ bias,
    const TRES* __restrict__ res,
    int M, int N, int K)
{
    __shared__ __align__(16) short As[128][72];  // 64 k + 8 pad
    __shared__ __align__(16) short Bs[128][72];
    const int tid  = threadIdx.x;
    const int lane = tid & 63;
    const int wave = tid >> 6;
    const int m0 = blockIdx.y * 128;
    const int n0 = blockIdx.x * 128;
    const int wm = (wave >> 1) * 64;
    const int wn = (wave & 1) * 64;
    const int lr = lane & 15;
    const int lq = lane >> 4;

    const int sr = tid >> 1;          // staging row 0..127
    const int sc = (tid & 1) * 32;    // staging k-offset (shorts)

    f32x4 acc[4][4] = {};

    for (int k0 = 0; k0 < K; k0 += 64) {
        const uint4* pa = (const uint4*)(A + (long)(m0 + sr) * lda + (k0 + sc));
        uint4 a0 = pa[0], a1 = pa[1], a2 = pa[2], a3 = pa[3];
        uint4 b0, b1, b2, b3;
        b0.x=b0.y=b0.z=b0.w=0; b1=b0; b2=b0; b3=b0;
        if (n0 + sr < N) {
            const uint4* pb = (const uint4*)(Bw + (long)(n0 + sr) * ldb + (k0 + sc));
            b0 = pb[0]; b1 = pb[1]; b2 = pb[2]; b3 = pb[3];
        }
        *(uint4*)&As[sr][sc +  0] = a0;
        *(uint4*)&As[sr][sc +  8] = a1;
        *(uint4*)&As[sr][sc + 16] = a2;
        *(uint4*)&As[sr][sc + 24] = a3;
        *(uint4*)&Bs[sr][sc +  0] = b0;
        *(uint4*)&Bs[sr][sc +  8] = b1;
        *(uint4*)&Bs[sr][sc + 16] = b2;
        *(uint4*)&Bs[sr][sc + 24] = b3;
        __syncthreads();

        #pragma unroll
        for (int kk = 0; kk < 2; ++kk) {
            bf16x8 af[4], bfr[4];
            #pragma unroll
            for (int i = 0; i < 4; ++i)
                af[i] = *(const bf16x8*)&As[wm + i * 16 + lr][kk * 32 + lq * 8];
            #pragma unroll
            for (int j = 0; j < 4; ++j)
                bfr[j] = *(const bf16x8*)&Bs[wn + j * 16 + lr][kk * 32 + lq * 8];
            #pragma unroll
            for (int i = 0; i < 4; ++i)
                #pragma unroll
                for (int j = 0; j < 4; ++j)
                    acc[i][j] = __builtin_amdgcn_mfma_f32_16x16x32_bf16(
                        af[i], bfr[j], acc[i][j], 0, 0, 0);
        }
        __syncthreads();
    }

    // Epilogue.  C/D layout: col = lane&15, row = (lane>>4)*4 + reg.
    #pragma unroll
    for (int j = 0; j < 4; ++j) {
        const int col = n0 + wn + j * 16 + lr;
        if (col >= N) continue;
        const float bv = bias ? b2f(bias[col]) : 0.f;
        #pragma unroll
        for (int i = 0; i < 4; ++i) {
            const int r0 = m0 + wm + i * 16 + lq * 4;
            #pragma unroll
            for (int r = 0; r < 4; ++r) {
                const long row = r0 + r;
                float v = acc[i][j][r] + bv;
                if constexpr (ACT == 1) v = 0.5f * v * (1.f + erff(v * 0.70710678118f));
                if constexpr (ACT == 2) v = (v > 20.f) ? v : log1pf(__expf(v));
                if (res) v += to_float(res[row * ldc + col]);
                store_out(&C[row * ldc + col], scrub(v));
            }
        }
    }
}

// ---------------------------------------------------------------------------
// Depthwise causal conv (window 4) + bias + silu.  u = xz[:, 0:2048].
// ---------------------------------------------------------------------------
__global__ __launch_bounds__(256) void conv_silu_kernel(
    const bf16* __restrict__ xz, const bf16* __restrict__ cw,
    const bf16* __restrict__ cb, bf16* __restrict__ uc)
{
    const int gid = blockIdx.x * 256 + threadIdx.x;   // over 2*1024*2048
    const int d   = gid & 2047;
    const int row = gid >> 11;                        // b*1024 + t
    const int t   = row & 1023;
    float acc = b2f(cb[d]);
    #pragma unroll
    for (int j = 0; j < 4; ++j) {
        const int tt = t - 3 + j;
        if (tt >= 0)
            acc += b2f(cw[d * 4 + j]) * b2f(xz[(long)(row - 3 + j) * 4096 + d]);
    }
    const float sg = 1.f / (1.f + __expf(-acc));
    uc[gid] = __float2bfloat16(acc * sg);
}

// ---------------------------------------------------------------------------
// Selective scan, v2: NO cross-lane ops in the recurrence loop.
//
// Round-5 version spent ~480 cy/step on 4 serially-dependent __shfl_xor
// (ds_bpermute latency, 1 wave/SIMD = nothing to hide it).  v2 moves the
// n-reduction out of the step loop: each lane writes p = h*C (+u*D on n==0)
// to sP[t][dl][n] (padded to 20 -> <=2-way bank aliasing, free per m136);
// a separate phase sums 16 n per (t,d) with aligned float4 LDS reads.
// Global staging is register-double-buffered (load chunk c+1 during compute
// of chunk c) to hide HBM latency at 1 block/CU.
// ---------------------------------------------------------------------------
__global__ __launch_bounds__(256) void scan_kernel(
    const bf16* __restrict__ delta,    // (B*L, 2048)
    const bf16* __restrict__ uc,       // (B*L, 2048)
    const bf16* __restrict__ dbc,      // (B*L, 96): dt | B | C
    const bf16* __restrict__ xz,       // (B*L, 4096): z at cols 2048+d
    const float* __restrict__ A_log,   // (2048, 16) fp32
    const float* __restrict__ Dp,      // (2048)     fp32
    bf16* __restrict__ y)              // (B*L, 2048)
{
    const int b   = blockIdx.y;
    const int d0  = blockIdx.x * 16;
    const int tid = threadIdx.x;
    const int n   = tid & 15;          // state index (phase 2)
    const int dl  = tid >> 4;          // channel 0..15 (phase 2)
    const int d   = d0 + dl;

    __shared__ float2 sDU[64][16];     // (dt, u)
    __shared__ float2 sBC[64][16];     // (B, C)
    __shared__ float  sZ [64][16];     // silu(z)
    __shared__ float  sP [64][16][20]; // h*C partials, pad 20 (16B-aligned rows)

    const float An = -expf(A_log[d * 16 + n]);
    const float Dd = Dp[d];
    float h = 0.f;
    const long rowbase = (long)b * 1024;

    // phase-3 lane mapping: dl3 = tid&15 (channel), t = k*16 + (tid>>4)
    const int dl3 = tid & 15;
    const int t3  = tid >> 4;
    const float zDd = 0.f; (void)zDd;

    // --- register staging buffers (chunk double-buffer) ---
    float rDT[4], rUV[4], rB[4], rC[4], rZ[4];
    auto load_chunk = [&](int t0c) {
        #pragma unroll
        for (int k = 0; k < 4; ++k) {
            const int i  = k * 256 + tid;
            const int tt = i >> 4, dd = i & 15;
            const long r = rowbase + t0c + tt;
            rDT[k] = b2f(delta[r * 2048 + d0 + dd]);
            rUV[k] = b2f(uc   [r * 2048 + d0 + dd]);
            rB[k]  = b2f(dbc  [r * 96 + 64 + dd]);
            rC[k]  = b2f(dbc  [r * 96 + 80 + dd]);
            rZ[k]  = b2f(xz   [r * 4096 + 2048 + d0 + dd]);
        }
    };
    auto store_chunk = [&]() {
        #pragma unroll
        for (int k = 0; k < 4; ++k) {
            const int i  = k * 256 + tid;
            const int tt = i >> 4, dd = i & 15;
            sDU[tt][dd] = float2{rDT[k], rUV[k]};
            sBC[tt][dd] = float2{rB[k], rC[k]};
            const float zz = rZ[k];
            sZ[tt][dd] = zz / (1.f + __expf(-zz));
        }
    };

    load_chunk(0);
    for (int t0 = 0; t0 < 1024; t0 += 64) {
        store_chunk();
        __syncthreads();
        if (t0 + 64 < 1024) load_chunk(t0 + 64);   // overlap w/ phase 2+3

        // ---- phase 2: recurrence, no cross-lane ----
        #pragma unroll 8
        for (int t = 0; t < 64; ++t) {
            const float2 du = sDU[t][dl];
            const float2 bc = sBC[t][n];
            const float a   = __expf(du.x * An);
            h = a * h + (du.x * du.y) * bc.x;
            float p = h * bc.y;
            if (n == 0) p += du.y * Dd;            // fold u*D into lane n==0
            sP[t][dl][n] = p;
        }
        __syncthreads();

        // ---- phase 3: reduce 16 n per (t, dl3), 4 outputs/lane ----
        #pragma unroll
        for (int k = 0; k < 4; ++k) {
            const int t = t3 + k * 16;
            const float4* pp = (const float4*)&sP[t][dl3][0];
            const float4 p0 = pp[0], p1 = pp[1], p2 = pp[2], p3 = pp[3];
            const float s = ((p0.x + p0.y) + (p0.z + p0.w))
                          + ((p1.x + p1.y) + (p1.z + p1.w))
                          + ((p2.x + p2.y) + (p2.z + p2.w))
                          + ((p3.x + p3.y) + (p3.z + p3.w));
            const float yv = s * sZ[t][dl3];
            y[(rowbase + t0 + t) * 2048 + d0 + dl3] = __float2bfloat16(yv);
        }
        __syncthreads();   // protect sDU/sBC/sZ/sP before next store_chunk
    }
}

// ---------------------------------------------------------------------------
extern "C" void kernel_launch(void* const* d_in, const int* in_sizes, int n_in,
                              void* d_out, int out_size, void* d_ws, size_t ws_size,
                              hipStream_t stream)
{
    char* ws = (char*)d_ws;
    const size_t MiB = 1048576;

    // Pipeline scratch (time-multiplexed overlays):
    bf16*  xn  = (bf16*)(ws);                    // [ 0, 4): (2048,1024) ln1 out
    bf16*  xz  = (bf16*)(ws +  4 * MiB);         // [ 4,20): (2048,4096) in_proj out
    bf16*  uc  = (bf16*)(ws + 20 * MiB);         // [20,28): (2048,2048) conv+silu out
    bf16*  dbc = (bf16*)(ws + 28 * MiB);         // [28,28.4): (2048,96)
    bf16*  dlb = (bf16*)(ws + 28 * MiB + 524288);// [28.5,36.5): delta; scan writes y in-place
    bf16*  yb  = dlb;                            //   (element-aliased, safe)
    float* hb  = (float*)(ws);                   // [ 0, 8): f32 resid (xn/xz dead at step 7)
    bf16*  hn  = (bf16*)(ws +  8 * MiB);         // [ 8,12): ln2 out (over dead xz)
    bf16*  gb  = (bf16*)(ws + 12 * MiB);         // [12,20): mlp1 out (over dead xz)
    unsigned short* cvt = (unsigned short*)(ws + 37 * MiB);  // [37, 61.8): bf16 inputs

    // fp32 originals used directly (residual-path accuracy):
    const float* xf     = (const float*)d_in[0];
    const float* A_logf = (const float*)d_in[9];
    const float* Dpf    = (const float*)d_in[10];

    // Converted-input pointers (element offsets per TOFF).
    const bf16* ln1_w      = (const bf16*)(cvt + 2097152);
    const bf16* ln1_b      = (const bf16*)(cvt + 2098176);
    const bf16* in_proj_w  = (const bf16*)(cvt + 2099200);
    const bf16* conv_w     = (const bf16*)(cvt + 6293504);
    const bf16* conv_b     = (const bf16*)(cvt + 6301696);
    const bf16* x_proj_w   = (const bf16*)(cvt + 6303744);
    const bf16* dt_proj_w  = (const bf16*)(cvt + 6500352);
    const bf16* dt_proj_b  = (const bf16*)(cvt + 6631424);
    const bf16* out_proj_w = (const bf16*)(cvt + 6668288);
    const bf16* ln2_w      = (const bf16*)(cvt + 8765440);
    const bf16* ln2_b      = (const bf16*)(cvt + 8766464);
    const bf16* mlp_w1     = (const bf16*)(cvt + 8767488);
    const bf16* mlp_b1     = (const bf16*)(cvt + 10864640);
    const bf16* mlp_w2     = (const bf16*)(cvt + 10866688);
    const bf16* mlp_b2     = (const bf16*)(cvt + 12963840);

    // 0. input normalization fp32 -> bf16
    Ptrs ptrs;
    for (int i = 0; i < 18; ++i) ptrs.p[i] = d_in[i];
    convert_kernel<<<6332, 256, 0, stream>>>(ptrs, cvt);

    // 1. LN1 (reads fp32 x directly)
    ln_kernel<float><<<2048, 256, 0, stream>>>(xf, ln1_w, ln1_b, xn);
    // 2. in_proj: xz = xn @ in_proj_w^T   (2048,4096,K=1024)
    gemm_bt<0, bf16, bf16><<<dim3(32, 16), 256, 0, stream>>>(
        xn, 1024, in_proj_w, 1024, xz, 4096, nullptr, (const bf16*)nullptr, 2048, 4096, 1024);
    // 3. depthwise causal conv + bias + silu -> uc
    conv_silu_kernel<<<16384, 256, 0, stream>>>(xz, conv_w, conv_b, uc);
    // 4. x_proj: dbc = uc @ x_proj_w^T    (2048,96,K=2048)
    gemm_bt<0, bf16, bf16><<<dim3(1, 16), 256, 0, stream>>>(
        uc, 2048, x_proj_w, 2048, dbc, 96, nullptr, (const bf16*)nullptr, 2048, 96, 2048);
    // 5. dt_proj + softplus: delta = softplus(dbc[:, :64] @ dt_proj_w^T + b)
    gemm_bt<2, bf16, bf16><<<dim3(16, 16), 256, 0, stream>>>(
        dbc, 96, dt_proj_w, 64, dlb, 2048, dt_proj_b, (const bf16*)nullptr, 2048, 2048, 64);
    // 6. selective scan -> yb (in-place over dlb)
    scan_kernel<<<dim3(128, 2), 256, 0, stream>>>(dlb, uc, dbc, xz, A_logf, Dpf, yb);
    // 7. out_proj + residual x (fp32): hb = yb @ out_proj_w^T + x
    gemm_bt<0, float, float><<<dim3(8, 16), 256, 0, stream>>>(
        yb, 2048, out_proj_w, 2048, hb, 1024, nullptr, xf, 2048, 1024, 2048);
    // 8. LN2
    ln_kernel<float><<<2048, 256, 0, stream>>>(hb, ln2_w, ln2_b, hn);
    // 9. MLP1 + gelu: gb = gelu(hn @ mlp_w1^T + b1)
    gemm_bt<1, bf16, bf16><<<dim3(16, 16), 256, 0, stream>>>(
        hn, 1024, mlp_w1, 1024, gb, 2048, mlp_b1, (const bf16*)nullptr, 2048, 2048, 1024);
    // 10. MLP2 + bias + residual h -> d_out (fp32)
    gemm_bt<0, float, float><<<dim3(8, 16), 256, 0, stream>>>(
        gb, 2048, mlp_w2, 2048, (float*)d_out, 1024, mlp_b2, hb, 2048, 1024, 2048);
}

// Round 7
// 362.842 us; speedup vs baseline: 1.7757x; 1.7488x over previous
//
#include <hip/hip_runtime.h>
#include <hip/hip_bf16.h>
#include <math.h>

typedef __hip_bfloat16 bf16;
typedef __attribute__((ext_vector_type(8))) short bf16x8;
typedef __attribute__((ext_vector_type(4))) float f32x4;

__device__ __forceinline__ float b2f(bf16 x) { return __bfloat162float(x); }
__device__ __forceinline__ float us2f(unsigned short u) {
    return __uint_as_float(((unsigned int)u) << 16);
}
__device__ __forceinline__ unsigned short f2us(float f) {
    bf16 t = __float2bfloat16(f);
    return *reinterpret_cast<unsigned short*>(&t);
}
__device__ __forceinline__ float scrub(float v) {
    return (v == v && fabsf(v) < 3.0e38f) ? v : 0.f;
}
__device__ __forceinline__ float to_float(float x) { return x; }
__device__ __forceinline__ float to_float(bf16 x) { return __bfloat162float(x); }
__device__ __forceinline__ void store_out(float* p, float v) { *p = v; }
__device__ __forceinline__ void store_out(bf16* p, float v) { *p = __float2bfloat16(v); }

// async global->LDS, 16 B per lane; LDS dest = wave-uniform base + lane*16
// (m97 pattern: 517->874 TF on the GEMM ladder).
__device__ __forceinline__ void cp16(const void* g, void* l) {
    __builtin_amdgcn_global_load_lds(
        (const __attribute__((address_space(1))) unsigned int*)g,
        (__attribute__((address_space(3))) unsigned int*)l, 16, 0, 0);
}

// ---------------------------------------------------------------------------
// Convert all 18 fp32 input tensors into one contiguous bf16 region.
// ---------------------------------------------------------------------------
struct Ptrs { const void* p[18]; };

__constant__ __device__ const long TOFF[19] = {
    0,         2097152,  2098176,  2099200,  6293504,  6301696,  6303744,
    6500352,   6631424,  6633472,  6666240,  6668288,  8765440,  8766464,
    8767488,   10864640, 10866688, 12963840, 12964864};

__global__ __launch_bounds__(256) void convert_kernel(
    Ptrs ptrs, unsigned short* __restrict__ dst)
{
    const long g = (long)blockIdx.x * 256 + threadIdx.x;
    if (g >= 1620608) return;            // 12,964,864 / 8
    const long e0 = g * 8;
    int t = 0;
    #pragma unroll
    for (int i = 1; i < 18; ++i) t += (e0 >= TOFF[i]) ? 1 : 0;
    const long local = e0 - TOFF[t];
    const float4* ps = (const float4*)((const float*)ptrs.p[t] + local);
    const float4 a = ps[0], b = ps[1];
    ushort4 o0, o1;
    o0.x = f2us(a.x); o0.y = f2us(a.y); o0.z = f2us(a.z); o0.w = f2us(a.w);
    o1.x = f2us(b.x); o1.y = f2us(b.y); o1.z = f2us(b.z); o1.w = f2us(b.w);
    *(ushort4*)(dst + e0)     = o0;
    *(ushort4*)(dst + e0 + 4) = o1;
}

// ---------------------------------------------------------------------------
// LayerNorm: one block per row of 1024, 256 threads x 4 elems.
// ---------------------------------------------------------------------------
template <typename TIN>
__global__ __launch_bounds__(256) void ln_kernel(
    const TIN* __restrict__ in, const bf16* __restrict__ gw,
    const bf16* __restrict__ gb, bf16* __restrict__ out)
{
    const int row = blockIdx.x;
    const int tid = threadIdx.x;
    float v[4];
    if constexpr (sizeof(TIN) == 2) {
        ushort4 raw = ((const ushort4*)((const unsigned short*)in + (long)row * 1024))[tid];
        v[0] = us2f(raw.x); v[1] = us2f(raw.y); v[2] = us2f(raw.z); v[3] = us2f(raw.w);
    } else {
        float4 raw = ((const float4*)((const float*)in + (long)row * 1024))[tid];
        v[0] = raw.x; v[1] = raw.y; v[2] = raw.z; v[3] = raw.w;
    }
    float s  = v[0] + v[1] + v[2] + v[3];
    float s2 = v[0]*v[0] + v[1]*v[1] + v[2]*v[2] + v[3]*v[3];
    #pragma unroll
    for (int o = 32; o > 0; o >>= 1) {
        s  += __shfl_xor(s, o);
        s2 += __shfl_xor(s2, o);
    }
    __shared__ float red[8];
    if ((tid & 63) == 0) { red[tid >> 6] = s; red[4 + (tid >> 6)] = s2; }
    __syncthreads();
    s  = red[0] + red[1] + red[2] + red[3];
    s2 = red[4] + red[5] + red[6] + red[7];
    const float mu  = s * (1.f / 1024.f);
    const float var = fmaxf(s2 * (1.f / 1024.f) - mu * mu, 0.f);
    const float rs  = rsqrtf(var + 1e-5f);
    const int c0 = tid * 4;
    ushort4 o;
    o.x = f2us((v[0] - mu) * rs * b2f(gw[c0 + 0]) + b2f(gb[c0 + 0]));
    o.y = f2us((v[1] - mu) * rs * b2f(gw[c0 + 1]) + b2f(gb[c0 + 1]));
    o.z = f2us((v[2] - mu) * rs * b2f(gw[c0 + 2]) + b2f(gb[c0 + 2]));
    o.w = f2us((v[3] - mu) * rs * b2f(gw[c0 + 3]) + b2f(gb[c0 + 3]));
    ((ushort4*)((unsigned short*)out + (long)row * 1024))[tid] = o;
}

// ---------------------------------------------------------------------------
// GEMM v2 (m97-style): C[M,N] = act(A[M,K] @ Bw[N,K]^T + bias) + res.
// global_load_lds width-16 staging into unpadded [B][64] LDS; BK=64;
// 4 waves as 2x2, wave tile (BM/2)x(BN/2) of 16x16x32 MFMAs.
// NG: guard B rows against N (x_proj, N=96; boundary is 8-row aligned).
// ---------------------------------------------------------------------------
template <int BM, int BN, int ACT, bool NG, typename TOUT, typename TRES>
__global__ __launch_bounds__(256) void gemm_as(
    const bf16* __restrict__ A, int lda,
    const bf16* __restrict__ Bw, int ldb,
    TOUT* __restrict__ C, int ldc,
    const bf16* __restrict__ bias,
    const TRES* __restrict__ res,
    int M, int N, int K)
{
    constexpr int AI = BM / 32;
    constexpr int BJ = BN / 32;
    __shared__ __align__(16) short As[BM * 64];
    __shared__ __align__(16) short Bs[BN * 64];
    const int tid  = threadIdx.x;
    const int lane = tid & 63;
    const int wv   = tid >> 6;
    const int m0 = blockIdx.y * BM;
    const int n0 = blockIdx.x * BN;
    const int wm = (wv >> 1) * (BM / 2);
    const int wn = (wv & 1) * (BN / 2);
    const int lr = lane & 15;
    const int lq = lane >> 4;
    const int grow = lane >> 3;         // row 0..7 within an 8-row group
    const int gcol = (lane & 7) * 8;    // 16B chunk (shorts)

    if (NG) {
        // one-time zero of OOB B rows (never re-written by skipped loads)
        const int z0 = (N - n0) * 64;
        uint4 z; z.x = z.y = z.z = z.w = 0;
        for (int s = z0 + tid * 8; s < BN * 64; s += 2048)
            *(uint4*)&Bs[s] = z;
    }

    f32x4 acc[AI][BJ] = {};

    for (int k0 = 0; k0 < K; k0 += 64) {
        #pragma unroll
        for (int g = 0; g < BM / 32; ++g) {
            const int gg = g * 4 + wv;   // wave-uniform 8-row group
            cp16(A + (long)(m0 + gg * 8 + grow) * lda + k0 + gcol, &As[gg * 512]);
        }
        #pragma unroll
        for (int g = 0; g < BN / 32; ++g) {
            const int gg = g * 4 + wv;
            if (!NG || n0 + gg * 8 < N)
                cp16(Bw + (long)(n0 + gg * 8 + grow) * ldb + k0 + gcol, &Bs[gg * 512]);
        }
        __syncthreads();   // compiler drains vmcnt before s_barrier (m97)

        #pragma unroll
        for (int kk = 0; kk < 2; ++kk) {
            bf16x8 af[AI], bfr[BJ];
            #pragma unroll
            for (int i = 0; i < AI; ++i)
                af[i] = *(const bf16x8*)&As[(wm + i * 16 + lr) * 64 + kk * 32 + lq * 8];
            #pragma unroll
            for (int j = 0; j < BJ; ++j)
                bfr[j] = *(const bf16x8*)&Bs[(wn + j * 16 + lr) * 64 + kk * 32 + lq * 8];
            #pragma unroll
            for (int i = 0; i < AI; ++i)
                #pragma unroll
                for (int j = 0; j < BJ; ++j)
                    acc[i][j] = __builtin_amdgcn_mfma_f32_16x16x32_bf16(
                        af[i], bfr[j], acc[i][j], 0, 0, 0);
        }
        __syncthreads();
    }

    // Epilogue.  C/D layout: col = lane&15, row = (lane>>4)*4 + reg.
    #pragma unroll
    for (int j = 0; j < BJ; ++j) {
        const int col = n0 + wn + j * 16 + lr;
        if (col >= N) continue;
        const float bv = bias ? b2f(bias[col]) : 0.f;
        #pragma unroll
        for (int i = 0; i < AI; ++i) {
            const int r0 = m0 + wm + i * 16 + lq * 4;
            #pragma unroll
            for (int r = 0; r < 4; ++r) {
                const long row = r0 + r;
                float v = acc[i][j][r] + bv;
                if (ACT == 1) v = 0.5f * v * (1.f + erff(v * 0.70710678118f));
                if (ACT == 2) v = (v > 20.f) ? v : log1pf(__expf(v));
                if (res) v += to_float(res[row * (long)ldc + col]);
                store_out(&C[row * (long)ldc + col], scrub(v));
            }
        }
    }
}

// ---------------------------------------------------------------------------
// Depthwise causal conv (window 4) + bias + silu.  u = xz[:, 0:2048].
// ---------------------------------------------------------------------------
__global__ __launch_bounds__(256) void conv_silu_kernel(
    const bf16* __restrict__ xz, const bf16* __restrict__ cw,
    const bf16* __restrict__ cb, bf16* __restrict__ uc)
{
    const int gid = blockIdx.x * 256 + threadIdx.x;   // over 2*1024*2048
    const int d   = gid & 2047;
    const int row = gid >> 11;                        // b*1024 + t
    const int t   = row & 1023;
    float acc = b2f(cb[d]);
    #pragma unroll
    for (int j = 0; j < 4; ++j) {
        const int tt = t - 3 + j;
        if (tt >= 0)
            acc += b2f(cw[d * 4 + j]) * b2f(xz[(long)(row - 3 + j) * 4096 + d]);
    }
    const float sg = 1.f / (1.f + __expf(-acc));
    uc[gid] = __float2bfloat16(acc * sg);
}

// ---------------------------------------------------------------------------
// Selective scan v3: phase-2 LDS reads register-double-buffered in 8-step
// batches; the exp/FMA prep is off the h-chain, so the serial core is just
// 64 chained FMAs per chunk.  No cross-lane ops anywhere.
// ---------------------------------------------------------------------------
__global__ __launch_bounds__(256) void scan_kernel(
    const bf16* __restrict__ delta,    // (B*L, 2048)
    const bf16* __restrict__ uc,       // (B*L, 2048)
    const bf16* __restrict__ dbc,      // (B*L, 96): dt | B | C
    const bf16* __restrict__ xz,       // (B*L, 4096): z at cols 2048+d
    const float* __restrict__ A_log,   // (2048, 16) fp32
    const float* __restrict__ Dp,      // (2048)     fp32
    bf16* __restrict__ y)              // (B*L, 2048)
{
    const int b   = blockIdx.y;
    const int d0  = blockIdx.x * 16;
    const int tid = threadIdx.x;
    const int n   = tid & 15;          // state index (phase 2)
    const int dl  = tid >> 4;          // channel 0..15 (phase 2)
    const int d   = d0 + dl;

    __shared__ float2 sDU[64][16];     // (dt, u)
    __shared__ float2 sBC[64][16];     // (B, C)
    __shared__ float  sZ [64][16];     // silu(z)
    __shared__ float  sP [64][16][20]; // h*C partials (pad 20)

    const float An = -expf(A_log[d * 16 + n]);
    const float Dd = Dp[d];
    float h = 0.f;
    const long rowbase = (long)b * 1024;

    const int dl3 = tid & 15;
    const int t3  = tid >> 4;

    float rDT[4], rUV[4], rB[4], rC[4], rZ[4];
    auto load_chunk = [&](int t0c) {
        #pragma unroll
        for (int k = 0; k < 4; ++k) {
            const int i  = k * 256 + tid;
            const int tt = i >> 4, dd = i & 15;
            const long r = rowbase + t0c + tt;
            rDT[k] = b2f(delta[r * 2048 + d0 + dd]);
            rUV[k] = b2f(uc   [r * 2048 + d0 + dd]);
            rB[k]  = b2f(dbc  [r * 96 + 64 + dd]);
            rC[k]  = b2f(dbc  [r * 96 + 80 + dd]);
            rZ[k]  = b2f(xz   [r * 4096 + 2048 + d0 + dd]);
        }
    };
    auto store_chunk = [&]() {
        #pragma unroll
        for (int k = 0; k < 4; ++k) {
            const int i  = k * 256 + tid;
            const int tt = i >> 4, dd = i & 15;
            sDU[tt][dd] = float2{rDT[k], rUV[k]};
            sBC[tt][dd] = float2{rB[k], rC[k]};
            const float zz = rZ[k];
            sZ[tt][dd] = zz / (1.f + __expf(-zz));
        }
    };

    load_chunk(0);
    for (int t0 = 0; t0 < 1024; t0 += 64) {
        store_chunk();
        __syncthreads();
        if (t0 + 64 < 1024) load_chunk(t0 + 64);

        // ---- phase 2: recurrence, reg-double-buffered LDS reads ----
        {
            float2 dua[8], bca[8], dub[8], bcb[8];
            #pragma unroll
            for (int t = 0; t < 8; ++t) { dua[t] = sDU[t][dl]; bca[t] = sBC[t][n]; }
            #pragma unroll
            for (int tb = 0; tb < 64; tb += 8) {
                if (tb < 56) {
                    #pragma unroll
                    for (int t = 0; t < 8; ++t) {
                        dub[t] = sDU[tb + 8 + t][dl];
                        bcb[t] = sBC[tb + 8 + t][n];
                    }
                }
                #pragma unroll
                for (int t = 0; t < 8; ++t) {
                    const float a = __expf(dua[t].x * An);
                    h = a * h + (dua[t].x * dua[t].y) * bca[t].x;
                    float p = h * bca[t].y;
                    if (n == 0) p += dua[t].y * Dd;
                    sP[tb + t][dl][n] = p;
                }
                #pragma unroll
                for (int t = 0; t < 8; ++t) { dua[t] = dub[t]; bca[t] = bcb[t]; }
            }
        }
        __syncthreads();

        // ---- phase 3: reduce 16 n per (t, dl3), 4 outputs/lane ----
        #pragma unroll
        for (int k = 0; k < 4; ++k) {
            const int t = t3 + k * 16;
            const float4* pp = (const float4*)&sP[t][dl3][0];
            const float4 p0 = pp[0], p1 = pp[1], p2 = pp[2], p3 = pp[3];
            const float s = ((p0.x + p0.y) + (p0.z + p0.w))
                          + ((p1.x + p1.y) + (p1.z + p1.w))
                          + ((p2.x + p2.y) + (p2.z + p2.w))
                          + ((p3.x + p3.y) + (p3.z + p3.w));
            const float yv = s * sZ[t][dl3];
            y[(rowbase + t0 + t) * 2048 + d0 + dl3] = __float2bfloat16(yv);
        }
        __syncthreads();
    }
}

// ---------------------------------------------------------------------------
extern "C" void kernel_launch(void* const* d_in, const int* in_sizes, int n_in,
                              void* d_out, int out_size, void* d_ws, size_t ws_size,
                              hipStream_t stream)
{
    char* ws = (char*)d_ws;
    const size_t MiB = 1048576;

    bf16*  xn  = (bf16*)(ws);                    // [ 0, 4): (2048,1024) ln1 out
    bf16*  xz  = (bf16*)(ws +  4 * MiB);         // [ 4,20): (2048,4096) in_proj out
    bf16*  uc  = (bf16*)(ws + 20 * MiB);         // [20,28): (2048,2048) conv+silu out
    bf16*  dbc = (bf16*)(ws + 28 * MiB);         // [28,28.4): (2048,96)
    bf16*  dlb = (bf16*)(ws + 28 * MiB + 524288);// [28.5,36.5): delta; scan writes y in-place
    bf16*  yb  = dlb;                            //   (element-aliased, safe)
    float* hb  = (float*)(ws);                   // [ 0, 8): f32 resid (xn/xz dead at step 7)
    bf16*  hn  = (bf16*)(ws +  8 * MiB);         // [ 8,12): ln2 out (over dead xz)
    bf16*  gb  = (bf16*)(ws + 12 * MiB);         // [12,20): mlp1 out (over dead xz)
    unsigned short* cvt = (unsigned short*)(ws + 37 * MiB);  // [37, 61.8): bf16 inputs

    const float* xf     = (const float*)d_in[0];
    const float* A_logf = (const float*)d_in[9];
    const float* Dpf    = (const float*)d_in[10];

    const bf16* ln1_w      = (const bf16*)(cvt + 2097152);
    const bf16* ln1_b      = (const bf16*)(cvt + 2098176);
    const bf16* in_proj_w  = (const bf16*)(cvt + 2099200);
    const bf16* conv_w     = (const bf16*)(cvt + 6293504);
    const bf16* conv_b     = (const bf16*)(cvt + 6301696);
    const bf16* x_proj_w   = (const bf16*)(cvt + 6303744);
    const bf16* dt_proj_w  = (const bf16*)(cvt + 6500352);
    const bf16* dt_proj_b  = (const bf16*)(cvt + 6631424);
    const bf16* out_proj_w = (const bf16*)(cvt + 6668288);
    const bf16* ln2_w      = (const bf16*)(cvt + 8765440);
    const bf16* ln2_b      = (const bf16*)(cvt + 8766464);
    const bf16* mlp_w1     = (const bf16*)(cvt + 8767488);
    const bf16* mlp_b1     = (const bf16*)(cvt + 10864640);
    const bf16* mlp_w2     = (const bf16*)(cvt + 10866688);
    const bf16* mlp_b2     = (const bf16*)(cvt + 12963840);

    // 0. input normalization fp32 -> bf16
    Ptrs ptrs;
    for (int i = 0; i < 18; ++i) ptrs.p[i] = d_in[i];
    convert_kernel<<<6332, 256, 0, stream>>>(ptrs, cvt);

    // 1. LN1 (reads fp32 x directly)
    ln_kernel<float><<<2048, 256, 0, stream>>>(xf, ln1_w, ln1_b, xn);
    // 2. in_proj: (2048,4096,K=1024)  128x128, 512 blocks (2/CU)
    gemm_as<128, 128, 0, false, bf16, bf16><<<dim3(32, 16), 256, 0, stream>>>(
        xn, 1024, in_proj_w, 1024, xz, 4096, nullptr, (const bf16*)nullptr, 2048, 4096, 1024);
    // 3. depthwise causal conv + bias + silu -> uc
    conv_silu_kernel<<<16384, 256, 0, stream>>>(xz, conv_w, conv_b, uc);
    // 4. x_proj: (2048,96,K=2048)  64x64 + N-guard, 64 blocks
    gemm_as<64, 64, 0, true, bf16, bf16><<<dim3(2, 32), 256, 0, stream>>>(
        uc, 2048, x_proj_w, 2048, dbc, 96, nullptr, (const bf16*)nullptr, 2048, 96, 2048);
    // 5. dt_proj + softplus: (2048,2048,K=64)  64x64, 1024 blocks (4/CU)
    gemm_as<64, 64, 2, false, bf16, bf16><<<dim3(32, 32), 256, 0, stream>>>(
        dbc, 96, dt_proj_w, 64, dlb, 2048, dt_proj_b, (const bf16*)nullptr, 2048, 2048, 64);
    // 6. selective scan -> yb (in-place over dlb)
    scan_kernel<<<dim3(128, 2), 256, 0, stream>>>(dlb, uc, dbc, xz, A_logf, Dpf, yb);
    // 7. out_proj + residual x (fp32): (2048,1024,K=2048)  64x64, 512 blocks
    gemm_as<64, 64, 0, false, float, float><<<dim3(16, 32), 256, 0, stream>>>(
        yb, 2048, out_proj_w, 2048, hb, 1024, nullptr, xf, 2048, 1024, 2048);
    // 8. LN2
    ln_kernel<float><<<2048, 256, 0, stream>>>(hb, ln2_w, ln2_b, hn);
    // 9. MLP1 + gelu: (2048,2048,K=1024)  64x64, 1024 blocks (4/CU)
    gemm_as<64, 64, 1, false, bf16, bf16><<<dim3(32, 32), 256, 0, stream>>>(
        hn, 1024, mlp_w1, 1024, gb, 2048, mlp_b1, (const bf16*)nullptr, 2048, 2048, 1024);
    // 10. MLP2 + bias + residual h -> d_out (fp32): 64x64, 512 blocks
    gemm_as<64, 64, 0, false, float, float><<<dim3(16, 32), 256, 0, stream>>>(
        gb, 2048, mlp_w2, 2048, (float*)d_out, 1024, mlp_b2, hb, 2048, 1024, 2048);
}